// Round 5
// baseline (1073.588 us; speedup 1.0000x reference)
//
#include <hip/hip_runtime.h>

#define N_NODES 100000
#define N_EDGES 1600000
#define HIDDEN 64
#define EDGE_DIM 16
#define N_LAYERS 3
#define N_GRAPHS 512
#define BN_EPS 1e-5f

#define CHUNK 2048
#define NCHUNK ((N_NODES + CHUNK - 1) / CHUNK)   // 49

// ---------------- CSR construction ----------------

__global__ void k_hist(const int* __restrict__ dst, int* __restrict__ hist) {
    int e = blockIdx.x * 256 + threadIdx.x;
    if (e < N_EDGES) atomicAdd(&hist[dst[e]], 1);
}

__global__ void k_scan_partial(const int* __restrict__ hist, int* __restrict__ partial) {
    __shared__ int sd[256];
    int c = blockIdx.x, t = threadIdx.x;
    int base = c * CHUNK + t * 8;
    int s = 0;
#pragma unroll
    for (int u = 0; u < 8; ++u) {
        int i = base + u;
        s += (i < N_NODES) ? hist[i] : 0;
    }
    sd[t] = s;
    __syncthreads();
    for (int d = 128; d > 0; d >>= 1) {
        if (t < d) sd[t] += sd[t + d];
        __syncthreads();
    }
    if (t == 0) partial[c] = sd[0];
}

__global__ void k_scan_base(const int* __restrict__ partial, int* __restrict__ cbase) {
    if (threadIdx.x == 0) {
        int r = 0;
        for (int c = 0; c < NCHUNK; ++c) { cbase[c] = r; r += partial[c]; }
    }
}

__global__ void k_scan_final(const int* __restrict__ hist, const int* __restrict__ cbase,
                             int* __restrict__ row_start, int* __restrict__ cursor) {
    __shared__ int sd[256];
    int c = blockIdx.x, t = threadIdx.x;
    int i0 = c * CHUNK + t * 8;
    int v[8];
    int s = 0;
#pragma unroll
    for (int u = 0; u < 8; ++u) {
        int i = i0 + u;
        v[u] = (i < N_NODES) ? hist[i] : 0;
        s += v[u];
    }
    sd[t] = s;
    __syncthreads();
    for (int d = 1; d < 256; d <<= 1) {
        int x = (t >= d) ? sd[t - d] : 0;
        __syncthreads();
        sd[t] += x;
        __syncthreads();
    }
    int run = cbase[c] + sd[t] - s;  // exclusive prefix for this thread
#pragma unroll
    for (int u = 0; u < 8; ++u) {
        int i = i0 + u;
        if (i <= N_NODES) { row_start[i] = run; cursor[i] = run; }
        run += v[u];
    }
}

// phase 1: scatter only 4B records (perm + src). Random 4B writes into 6.4MB
// buffers are absorbed by L2/L3 (write-back bounds HBM amplification by buffer
// size, not access count) — avoids the 2x full-row scatter amplification.
__global__ void k_fill_perm(const int* __restrict__ edge_index, int* __restrict__ cursor,
                            int* __restrict__ perm, int* __restrict__ src_sorted) {
    int e = blockIdx.x * 256 + threadIdx.x;
    if (e >= N_EDGES) return;
    int d = edge_index[N_EDGES + e];
    int p = atomicAdd(&cursor[d], 1);
    perm[p] = e;
    src_sorted[p] = edge_index[e];
}

// phase 2: gather ea rows into sorted order. 4 threads per edge-row:
// random 16B reads (4 lanes cover one 64B row -> one coalesced request),
// fully-coalesced full-line writes (no amplification).
__global__ __launch_bounds__(256) void k_gather_ea(const int* __restrict__ perm,
        const float* __restrict__ ea, float* __restrict__ ea_sorted) {
    int gid = blockIdx.x * 256 + threadIdx.x;
    if (gid >= N_EDGES * 4) return;
    int p = gid >> 2, part = gid & 3;
    int e = perm[p];
    float4 v = ((const float4*)(ea + (size_t)e * 16))[part];
    ((float4*)(ea_sorted + (size_t)p * 16))[part] = v;
}

// ---------------- per-layer kernels ----------------

// wave-per-node edge aggregation: hin[n][j] = z[n][j] + sum_e relu(z[src][j] + (ea@We+be)[j])
// ea in CSR-sorted order (row p = position p). 8-wide unroll for latency hiding.
__global__ __launch_bounds__(256) void k_aggregate(
        const float* __restrict__ z, int zstride,
        const float* __restrict__ We, const float* __restrict__ be,
        const int* __restrict__ row_start,
        const int* __restrict__ srcs, const float* __restrict__ ea,
        float* __restrict__ hin) {
    int gid = blockIdx.x * 256 + threadIdx.x;
    int node = __builtin_amdgcn_readfirstlane(gid >> 6);
    int lane = threadIdx.x & 63;
    if (node >= N_NODES) return;
    float w[16];
#pragma unroll
    for (int k = 0; k < 16; ++k) w[k] = We[k * 64 + lane];
    float bl = be[lane];
    int p0 = row_start[node], p1 = row_start[node + 1];
    float acc = 0.f;
    int p = p0;
    // 8 independent z-gathers + 8 ea rows in flight
    for (; p + 8 <= p1; p += 8) {
        int s[8];
        float zv[8], ev[8];
#pragma unroll
        for (int u = 0; u < 8; ++u) s[u] = srcs[p + u];
#pragma unroll
        for (int u = 0; u < 8; ++u) zv[u] = z[(size_t)s[u] * zstride + lane];
#pragma unroll
        for (int u = 0; u < 8; ++u) {
            const float* er = ea + (size_t)(p + u) * 16;
            float e = bl;
#pragma unroll
            for (int k = 0; k < 16; ++k) e = fmaf(er[k], w[k], e);
            ev[u] = e;
        }
#pragma unroll
        for (int u = 0; u < 8; ++u) acc += fmaxf(zv[u] + ev[u], 0.f);
    }
    for (; p + 4 <= p1; p += 4) {
        int s[4];
        float zv[4], ev[4];
#pragma unroll
        for (int u = 0; u < 4; ++u) s[u] = srcs[p + u];
#pragma unroll
        for (int u = 0; u < 4; ++u) zv[u] = z[(size_t)s[u] * zstride + lane];
#pragma unroll
        for (int u = 0; u < 4; ++u) {
            const float* er = ea + (size_t)(p + u) * 16;
            float e = bl;
#pragma unroll
            for (int k = 0; k < 16; ++k) e = fmaf(er[k], w[k], e);
            ev[u] = e;
        }
#pragma unroll
        for (int u = 0; u < 4; ++u) acc += fmaxf(zv[u] + ev[u], 0.f);
    }
    for (; p < p1; ++p) {
        int s = srcs[p];
        const float* er = ea + (size_t)p * 16;
        float zv = z[(size_t)s * zstride + lane];
        float ev = bl;
#pragma unroll
        for (int k = 0; k < 16; ++k) ev = fmaf(er[k], w[k], ev);
        acc += fmaxf(zv + ev, 0.f);
    }
    float zself = z[(size_t)node * zstride + lane];
    hin[(size_t)node * 64 + lane] = zself + acc;
}

// thread-per-node MLP: hout = relu(relu(hin@W1+b1)@W2+b2)
__global__ __launch_bounds__(256) void k_mlp(
        const float* __restrict__ hin,
        const float* __restrict__ W1, const float* __restrict__ b1,
        const float* __restrict__ W2, const float* __restrict__ b2,
        float* __restrict__ hout) {
    int n = blockIdx.x * 256 + threadIdx.x;
    if (n >= N_NODES) return;
    const float4* __restrict__ hv = (const float4*)(hin + (size_t)n * 64);
    float t[64];
#pragma unroll
    for (int j = 0; j < 64; ++j) t[j] = b1[j];
    for (int kc = 0; kc < 16; ++kc) {
        float4 h4 = hv[kc];
        const float* wr = W1 + kc * 4 * 64;
#pragma unroll
        for (int j = 0; j < 64; ++j) t[j] = fmaf(h4.x, wr[j], t[j]);
#pragma unroll
        for (int j = 0; j < 64; ++j) t[j] = fmaf(h4.y, wr[64 + j], t[j]);
#pragma unroll
        for (int j = 0; j < 64; ++j) t[j] = fmaf(h4.z, wr[128 + j], t[j]);
#pragma unroll
        for (int j = 0; j < 64; ++j) t[j] = fmaf(h4.w, wr[192 + j], t[j]);
    }
#pragma unroll
    for (int j = 0; j < 64; ++j) t[j] = fmaxf(t[j], 0.f);
    float o[64];
#pragma unroll
    for (int j = 0; j < 64; ++j) o[j] = b2[j];
#pragma unroll
    for (int k = 0; k < 64; ++k) {
        const float* wr = W2 + k * 64;
        float tk = t[k];
#pragma unroll
        for (int j = 0; j < 64; ++j) o[j] = fmaf(tk, wr[j], o[j]);
    }
    float4* ov = (float4*)(hout + (size_t)n * 64);
#pragma unroll
    for (int i = 0; i < 16; ++i) {
        float4 v;
        v.x = fmaxf(o[4 * i + 0], 0.f);
        v.y = fmaxf(o[4 * i + 1], 0.f);
        v.z = fmaxf(o[4 * i + 2], 0.f);
        v.w = fmaxf(o[4 * i + 3], 0.f);
        ov[i] = v;
    }
}

// per-channel sum / sumsq over all nodes
__global__ __launch_bounds__(256) void k_stats(const float* __restrict__ h,
                                               float* __restrict__ ssum, float* __restrict__ ssq) {
    __shared__ float ls[64], lq[64];
    int tid = blockIdx.x * 256 + threadIdx.x;
    int nth = gridDim.x * 256;
    float4 s = {0, 0, 0, 0}, q = {0, 0, 0, 0};
    const float4* hv = (const float4*)h;
    for (int i = tid; i < N_NODES * 16; i += nth) {
        float4 v = hv[i];
        s.x += v.x; s.y += v.y; s.z += v.z; s.w += v.w;
        q.x += v.x * v.x; q.y += v.y * v.y; q.z += v.z * v.z; q.w += v.w * v.w;
    }
    if (threadIdx.x < 64) { ls[threadIdx.x] = 0.f; lq[threadIdx.x] = 0.f; }
    __syncthreads();
    int j = (threadIdx.x & 15) * 4;
    atomicAdd(&ls[j + 0], s.x); atomicAdd(&ls[j + 1], s.y);
    atomicAdd(&ls[j + 2], s.z); atomicAdd(&ls[j + 3], s.w);
    atomicAdd(&lq[j + 0], q.x); atomicAdd(&lq[j + 1], q.y);
    atomicAdd(&lq[j + 2], q.z); atomicAdd(&lq[j + 3], q.w);
    __syncthreads();
    if (threadIdx.x < 64) {
        atomicAdd(&ssum[threadIdx.x], ls[threadIdx.x]);
        atomicAdd(&ssq[threadIdx.x], lq[threadIdx.x]);
    }
}

// normalize (BN finalize folded in) and write the zz slice (stride 192)
__global__ __launch_bounds__(256) void k_norm(const float* __restrict__ h,
        const float* __restrict__ ssum, const float* __restrict__ ssq,
        const float* __restrict__ gamma, const float* __restrict__ beta,
        float* __restrict__ zzslice) {
    int i = blockIdx.x * 256 + threadIdx.x;  // float4 index, N*16 total
    if (i >= N_NODES * 16) return;
    int n = i >> 4, j4 = i & 15;
    int j = j4 * 4;
    float4 v = ((const float4*)h)[i];
    float out[4];
#pragma unroll
    for (int u = 0; u < 4; ++u) {
        float mean = ssum[j + u] * (1.f / N_NODES);
        float var = ssq[j + u] * (1.f / N_NODES) - mean * mean;
        float scale = gamma[j + u] * rsqrtf(var + BN_EPS);
        float shift = beta[j + u] - mean * scale;
        float hv = (u == 0) ? v.x : (u == 1) ? v.y : (u == 2) ? v.z : v.w;
        out[u] = fmaf(hv, scale, shift);
    }
    float4 r = {out[0], out[1], out[2], out[3]};
    *(float4*)(zzslice + (size_t)n * 192 + j4 * 4) = r;
}

// segment-sum over sorted batch: run-length accumulate, atomic per run.
#define GNODES 64
__global__ __launch_bounds__(192) void k_graph(const float* __restrict__ zz,
                                               const int* __restrict__ batch, float* __restrict__ g) {
    int j = threadIdx.x;  // 0..191; 192 floats = exactly one 768B row -> coalesced
    int n0 = blockIdx.x * GNODES;
    int n1 = n0 + GNODES;
    if (n1 > N_NODES) n1 = N_NODES;
    if (n0 >= N_NODES) return;
    float acc = 0.f;
    int cur = batch[n0];
    for (int n = n0; n < n1; ++n) {
        int b = batch[n];
        if (b != cur) {
            atomicAdd(&g[(size_t)cur * 192 + j], acc);
            acc = 0.f;
            cur = b;
        }
        acc += zz[(size_t)n * 192 + j];
    }
    atomicAdd(&g[(size_t)cur * 192 + j], acc);
}

// ---------------- launch ----------------

extern "C" void kernel_launch(void* const* d_in, const int* in_sizes, int n_in,
                              void* d_out, int out_size, void* d_ws, size_t ws_size,
                              hipStream_t stream) {
    const float* x         = (const float*)d_in[0];
    const float* edge_attr = (const float*)d_in[1];
    const float* We        = (const float*)d_in[2];
    const float* be        = (const float*)d_in[3];
    const float* W1        = (const float*)d_in[4];
    const float* b1        = (const float*)d_in[5];
    const float* W2        = (const float*)d_in[6];
    const float* b2        = (const float*)d_in[7];
    const float* gamma     = (const float*)d_in[8];
    const float* beta      = (const float*)d_in[9];
    const int* edge_index  = (const int*)d_in[10];
    const int* batch       = (const int*)d_in[11];

    float* zz = (float*)d_out;
    float* g  = zz + (size_t)N_NODES * 192;

    char* ws = (char*)d_ws;
    size_t off = 0;
    auto alloc = [&](size_t bytes) {
        void* p = ws + off;
        off = (off + bytes + 255) & ~(size_t)255;
        return p;
    };
    int* hist       = (int*)alloc((size_t)N_NODES * 4);
    int* row_start  = (int*)alloc((size_t)(N_NODES + 1) * 4);
    int* cursor     = (int*)alloc((size_t)(N_NODES + 1) * 4);
    int* partial    = (int*)alloc(64 * 4);
    int* cbase      = (int*)alloc(64 * 4);
    int* perm       = (int*)alloc((size_t)N_EDGES * 4);
    int* src_sorted = (int*)alloc((size_t)N_EDGES * 4);
    float* hin      = (float*)alloc((size_t)N_NODES * 64 * 4);
    float* hout     = (float*)alloc((size_t)N_NODES * 64 * 4);
    float* ssum     = (float*)alloc((size_t)N_LAYERS * 64 * 4);
    float* ssq      = (float*)alloc((size_t)N_LAYERS * 64 * 4);
    float* ea_sorted = (float*)alloc((size_t)N_EDGES * 16 * 4);   // 102.4 MB

    // CSR build
    hipMemsetAsync(hist, 0, (size_t)N_NODES * 4, stream);
    k_hist<<<(N_EDGES + 255) / 256, 256, 0, stream>>>(edge_index + N_EDGES, hist);
    k_scan_partial<<<NCHUNK, 256, 0, stream>>>(hist, partial);
    k_scan_base<<<1, 64, 0, stream>>>(partial, cbase);
    k_scan_final<<<NCHUNK, 256, 0, stream>>>(hist, cbase, row_start, cursor);
    k_fill_perm<<<(N_EDGES + 255) / 256, 256, 0, stream>>>(
        edge_index, cursor, perm, src_sorted);
    k_gather_ea<<<(N_EDGES * 4 + 255) / 256, 256, 0, stream>>>(
        perm, edge_attr, ea_sorted);

    hipMemsetAsync(g, 0, (size_t)N_GRAPHS * 192 * 4, stream);
    hipMemsetAsync(ssum, 0, (size_t)N_LAYERS * 64 * 4, stream);
    hipMemsetAsync(ssq, 0, (size_t)N_LAYERS * 64 * 4, stream);

    for (int l = 0; l < N_LAYERS; ++l) {
        const float* zptr = (l == 0) ? x : (zz + (size_t)(l - 1) * 64);
        int zstride = (l == 0) ? 64 : 192;
        k_aggregate<<<(N_NODES * 64 + 255) / 256, 256, 0, stream>>>(
            zptr, zstride, We + (size_t)l * EDGE_DIM * 64, be + (size_t)l * 64,
            row_start, src_sorted, ea_sorted, hin);
        k_mlp<<<(N_NODES + 255) / 256, 256, 0, stream>>>(
            hin, W1 + (size_t)l * 4096, b1 + (size_t)l * 64,
            W2 + (size_t)l * 4096, b2 + (size_t)l * 64, hout);
        k_stats<<<256, 256, 0, stream>>>(hout, ssum + l * 64, ssq + l * 64);
        k_norm<<<(N_NODES * 16 + 255) / 256, 256, 0, stream>>>(
            hout, ssum + l * 64, ssq + l * 64,
            gamma + (size_t)l * 64, beta + (size_t)l * 64, zz + (size_t)l * 64);
    }
    k_graph<<<(N_NODES + GNODES - 1) / GNODES, 192, 0, stream>>>(zz, batch, g);
}

// Round 6
// 997.448 us; speedup vs baseline: 1.0763x; 1.0763x over previous
//
#include <hip/hip_runtime.h>

#define N_NODES 100000
#define N_EDGES 1600000
#define HIDDEN 64
#define EDGE_DIM 16
#define N_LAYERS 3
#define N_GRAPHS 512
#define BN_EPS 1e-5f

#define CHUNK 2048
#define NCHUNK ((N_NODES + CHUNK - 1) / CHUNK)   // 49

typedef _Float16 h2 __attribute__((ext_vector_type(2)));
typedef _Float16 h4 __attribute__((ext_vector_type(4)));

// ---------------- CSR construction ----------------

__global__ void k_hist(const int* __restrict__ dst, int* __restrict__ hist) {
    int e = blockIdx.x * 256 + threadIdx.x;
    if (e < N_EDGES) atomicAdd(&hist[dst[e]], 1);
}

__global__ void k_scan_partial(const int* __restrict__ hist, int* __restrict__ partial) {
    __shared__ int sd[256];
    int c = blockIdx.x, t = threadIdx.x;
    int base = c * CHUNK + t * 8;
    int s = 0;
#pragma unroll
    for (int u = 0; u < 8; ++u) {
        int i = base + u;
        s += (i < N_NODES) ? hist[i] : 0;
    }
    sd[t] = s;
    __syncthreads();
    for (int d = 128; d > 0; d >>= 1) {
        if (t < d) sd[t] += sd[t + d];
        __syncthreads();
    }
    if (t == 0) partial[c] = sd[0];
}

__global__ void k_scan_base(const int* __restrict__ partial, int* __restrict__ cbase) {
    if (threadIdx.x == 0) {
        int r = 0;
        for (int c = 0; c < NCHUNK; ++c) { cbase[c] = r; r += partial[c]; }
    }
}

__global__ void k_scan_final(const int* __restrict__ hist, const int* __restrict__ cbase,
                             int* __restrict__ row_start, int* __restrict__ cursor) {
    __shared__ int sd[256];
    int c = blockIdx.x, t = threadIdx.x;
    int i0 = c * CHUNK + t * 8;
    int v[8];
    int s = 0;
#pragma unroll
    for (int u = 0; u < 8; ++u) {
        int i = i0 + u;
        v[u] = (i < N_NODES) ? hist[i] : 0;
        s += v[u];
    }
    sd[t] = s;
    __syncthreads();
    for (int d = 1; d < 256; d <<= 1) {
        int x = (t >= d) ? sd[t - d] : 0;
        __syncthreads();
        sd[t] += x;
        __syncthreads();
    }
    int run = cbase[c] + sd[t] - s;  // exclusive prefix for this thread
#pragma unroll
    for (int u = 0; u < 8; ++u) {
        int i = i0 + u;
        if (i <= N_NODES) { row_start[i] = run; cursor[i] = run; }
        run += v[u];
    }
}

// single 8B-record scatter: es_sorted[p] = {edge id, src}. One dirty sector
// per record (vs two with separate 4B perm/src scatters).
__global__ void k_fill_es(const int* __restrict__ edge_index, int* __restrict__ cursor,
                          int2* __restrict__ es_sorted) {
    int e = blockIdx.x * 256 + threadIdx.x;
    if (e >= N_EDGES) return;
    int s = edge_index[e];
    int d = edge_index[N_EDGES + e];
    int p = atomicAdd(&cursor[d], 1);
    es_sorted[p] = make_int2(e, s);
}

// gather ea rows into sorted order, converting f32 -> f16 (halves all
// downstream traffic). 4 threads/edge: 16B random reads (4 lanes cover one
// 64B row -> one request), fully-coalesced 8B f16 writes.
// Also emits compact src_sorted coalesced.
__global__ __launch_bounds__(256) void k_gather(const int2* __restrict__ es,
        const float* __restrict__ ea, _Float16* __restrict__ ea16,
        int* __restrict__ src_sorted) {
    int gid = blockIdx.x * 256 + threadIdx.x;
    if (gid >= N_EDGES * 4) return;
    int p = gid >> 2, part = gid & 3;
    int2 r = es[p];
    if (part == 0) src_sorted[p] = r.y;
    float4 v = ((const float4*)(ea + (size_t)r.x * 16))[part];
    h4 o = {(_Float16)v.x, (_Float16)v.y, (_Float16)v.z, (_Float16)v.w};
    ((h4*)(ea16 + (size_t)p * 16))[part] = o;
}

// x (f32, [N,64]) -> x16 (f16 compact copy) for the gather path
__global__ __launch_bounds__(256) void k_cvt_x(const float* __restrict__ x,
                                               _Float16* __restrict__ x16) {
    int i = blockIdx.x * 256 + threadIdx.x;   // float4 units, N*16 total
    if (i >= N_NODES * 16) return;
    float4 v = ((const float4*)x)[i];
    h4 o = {(_Float16)v.x, (_Float16)v.y, (_Float16)v.z, (_Float16)v.w};
    ((h4*)x16)[i] = o;
}

// ---------------- per-layer kernels ----------------

// wave-per-node edge aggregation:
//   hin[n][j] = zself[n][j] + sum_p relu(z16[src[p]][j] + dot(ea16[p], We[:,j]) + be[j])
// Messages use the f16 path (v_dot2_f32_f16, f32 accumulate); self term is exact f32.
__global__ __launch_bounds__(256) void k_aggregate(
        const float* __restrict__ zself_base, int zstride,
        const _Float16* __restrict__ z16,
        const float* __restrict__ We, const float* __restrict__ be,
        const int* __restrict__ row_start,
        const int* __restrict__ srcs, const _Float16* __restrict__ ea16,
        float* __restrict__ hin) {
    int gid = blockIdx.x * 256 + threadIdx.x;
    int node = __builtin_amdgcn_readfirstlane(gid >> 6);
    int lane = threadIdx.x & 63;
    if (node >= N_NODES) return;
    // per-lane column of We as 8 half2 pairs
    h2 w2[8];
#pragma unroll
    for (int i = 0; i < 8; ++i) {
        h2 t;
        t[0] = (_Float16)We[(2 * i) * 64 + lane];
        t[1] = (_Float16)We[(2 * i + 1) * 64 + lane];
        w2[i] = t;
    }
    float bl = be[lane];
    int p0 = row_start[node], p1 = row_start[node + 1];
    float acc = 0.f;
    int p = p0;
    for (; p + 8 <= p1; p += 8) {
        int s[8];
        float zv[8], ev[8];
#pragma unroll
        for (int u = 0; u < 8; ++u) s[u] = srcs[p + u];
#pragma unroll
        for (int u = 0; u < 8; ++u) zv[u] = (float)z16[(size_t)s[u] * 64 + lane];
#pragma unroll
        for (int u = 0; u < 8; ++u) {
            const h2* row = (const h2*)(ea16 + (size_t)(p + u) * 16);
            float e = bl;
#pragma unroll
            for (int i = 0; i < 8; ++i) e = __builtin_amdgcn_fdot2(row[i], w2[i], e, false);
            ev[u] = e;
        }
#pragma unroll
        for (int u = 0; u < 8; ++u) acc += fmaxf(zv[u] + ev[u], 0.f);
    }
    for (; p + 4 <= p1; p += 4) {
        int s[4];
        float zv[4], ev[4];
#pragma unroll
        for (int u = 0; u < 4; ++u) s[u] = srcs[p + u];
#pragma unroll
        for (int u = 0; u < 4; ++u) zv[u] = (float)z16[(size_t)s[u] * 64 + lane];
#pragma unroll
        for (int u = 0; u < 4; ++u) {
            const h2* row = (const h2*)(ea16 + (size_t)(p + u) * 16);
            float e = bl;
#pragma unroll
            for (int i = 0; i < 8; ++i) e = __builtin_amdgcn_fdot2(row[i], w2[i], e, false);
            ev[u] = e;
        }
#pragma unroll
        for (int u = 0; u < 4; ++u) acc += fmaxf(zv[u] + ev[u], 0.f);
    }
    for (; p < p1; ++p) {
        int s = srcs[p];
        const h2* row = (const h2*)(ea16 + (size_t)p * 16);
        float zv = (float)z16[(size_t)s * 64 + lane];
        float e = bl;
#pragma unroll
        for (int i = 0; i < 8; ++i) e = __builtin_amdgcn_fdot2(row[i], w2[i], e, false);
        acc += fmaxf(zv + e, 0.f);
    }
    float zself = zself_base[(size_t)node * zstride + lane];
    hin[(size_t)node * 64 + lane] = zself + acc;
}

// thread-per-node MLP: hout = relu(relu(hin@W1+b1)@W2+b2)
__global__ __launch_bounds__(256) void k_mlp(
        const float* __restrict__ hin,
        const float* __restrict__ W1, const float* __restrict__ b1,
        const float* __restrict__ W2, const float* __restrict__ b2,
        float* __restrict__ hout) {
    int n = blockIdx.x * 256 + threadIdx.x;
    if (n >= N_NODES) return;
    const float4* __restrict__ hv = (const float4*)(hin + (size_t)n * 64);
    float t[64];
#pragma unroll
    for (int j = 0; j < 64; ++j) t[j] = b1[j];
    for (int kc = 0; kc < 16; ++kc) {
        float4 h4v = hv[kc];
        const float* wr = W1 + kc * 4 * 64;
#pragma unroll
        for (int j = 0; j < 64; ++j) t[j] = fmaf(h4v.x, wr[j], t[j]);
#pragma unroll
        for (int j = 0; j < 64; ++j) t[j] = fmaf(h4v.y, wr[64 + j], t[j]);
#pragma unroll
        for (int j = 0; j < 64; ++j) t[j] = fmaf(h4v.z, wr[128 + j], t[j]);
#pragma unroll
        for (int j = 0; j < 64; ++j) t[j] = fmaf(h4v.w, wr[192 + j], t[j]);
    }
#pragma unroll
    for (int j = 0; j < 64; ++j) t[j] = fmaxf(t[j], 0.f);
    float o[64];
#pragma unroll
    for (int j = 0; j < 64; ++j) o[j] = b2[j];
#pragma unroll
    for (int k = 0; k < 64; ++k) {
        const float* wr = W2 + k * 64;
        float tk = t[k];
#pragma unroll
        for (int j = 0; j < 64; ++j) o[j] = fmaf(tk, wr[j], o[j]);
    }
    float4* ov = (float4*)(hout + (size_t)n * 64);
#pragma unroll
    for (int i = 0; i < 16; ++i) {
        float4 v;
        v.x = fmaxf(o[4 * i + 0], 0.f);
        v.y = fmaxf(o[4 * i + 1], 0.f);
        v.z = fmaxf(o[4 * i + 2], 0.f);
        v.w = fmaxf(o[4 * i + 3], 0.f);
        ov[i] = v;
    }
}

// per-channel sum / sumsq over all nodes
__global__ __launch_bounds__(256) void k_stats(const float* __restrict__ h,
                                               float* __restrict__ ssum, float* __restrict__ ssq) {
    __shared__ float ls[64], lq[64];
    int tid = blockIdx.x * 256 + threadIdx.x;
    int nth = gridDim.x * 256;
    float4 s = {0, 0, 0, 0}, q = {0, 0, 0, 0};
    const float4* hv = (const float4*)h;
    for (int i = tid; i < N_NODES * 16; i += nth) {
        float4 v = hv[i];
        s.x += v.x; s.y += v.y; s.z += v.z; s.w += v.w;
        q.x += v.x * v.x; q.y += v.y * v.y; q.z += v.z * v.z; q.w += v.w * v.w;
    }
    if (threadIdx.x < 64) { ls[threadIdx.x] = 0.f; lq[threadIdx.x] = 0.f; }
    __syncthreads();
    int j = (threadIdx.x & 15) * 4;
    atomicAdd(&ls[j + 0], s.x); atomicAdd(&ls[j + 1], s.y);
    atomicAdd(&ls[j + 2], s.z); atomicAdd(&ls[j + 3], s.w);
    atomicAdd(&lq[j + 0], q.x); atomicAdd(&lq[j + 1], q.y);
    atomicAdd(&lq[j + 2], q.z); atomicAdd(&lq[j + 3], q.w);
    __syncthreads();
    if (threadIdx.x < 64) {
        atomicAdd(&ssum[threadIdx.x], ls[threadIdx.x]);
        atomicAdd(&ssq[threadIdx.x], lq[threadIdx.x]);
    }
}

// normalize (BN finalize folded in), write zz slice (stride 192) and optional
// compact f16 copy for the next layer's gather path
__global__ __launch_bounds__(256) void k_norm(const float* __restrict__ h,
        const float* __restrict__ ssum, const float* __restrict__ ssq,
        const float* __restrict__ gamma, const float* __restrict__ beta,
        float* __restrict__ zzslice, _Float16* __restrict__ z16out) {
    int i = blockIdx.x * 256 + threadIdx.x;  // float4 index, N*16 total
    if (i >= N_NODES * 16) return;
    int n = i >> 4, j4 = i & 15;
    int j = j4 * 4;
    float4 v = ((const float4*)h)[i];
    float out[4];
#pragma unroll
    for (int u = 0; u < 4; ++u) {
        float mean = ssum[j + u] * (1.f / N_NODES);
        float var = ssq[j + u] * (1.f / N_NODES) - mean * mean;
        float scale = gamma[j + u] * rsqrtf(var + BN_EPS);
        float shift = beta[j + u] - mean * scale;
        float hv = (u == 0) ? v.x : (u == 1) ? v.y : (u == 2) ? v.z : v.w;
        out[u] = fmaf(hv, scale, shift);
    }
    float4 r = {out[0], out[1], out[2], out[3]};
    *(float4*)(zzslice + (size_t)n * 192 + j4 * 4) = r;
    if (z16out) {
        h4 o = {(_Float16)out[0], (_Float16)out[1], (_Float16)out[2], (_Float16)out[3]};
        ((h4*)(z16out + (size_t)n * 64 + j))[0] = o;
    }
}

// segment-sum over sorted batch: run-length accumulate, atomic per run.
#define GNODES 64
__global__ __launch_bounds__(192) void k_graph(const float* __restrict__ zz,
                                               const int* __restrict__ batch, float* __restrict__ g) {
    int j = threadIdx.x;  // 0..191; 192 floats = exactly one 768B row -> coalesced
    int n0 = blockIdx.x * GNODES;
    int n1 = n0 + GNODES;
    if (n1 > N_NODES) n1 = N_NODES;
    if (n0 >= N_NODES) return;
    float acc = 0.f;
    int cur = batch[n0];
    for (int n = n0; n < n1; ++n) {
        int b = batch[n];
        if (b != cur) {
            atomicAdd(&g[(size_t)cur * 192 + j], acc);
            acc = 0.f;
            cur = b;
        }
        acc += zz[(size_t)n * 192 + j];
    }
    atomicAdd(&g[(size_t)cur * 192 + j], acc);
}

// ---------------- launch ----------------

extern "C" void kernel_launch(void* const* d_in, const int* in_sizes, int n_in,
                              void* d_out, int out_size, void* d_ws, size_t ws_size,
                              hipStream_t stream) {
    const float* x         = (const float*)d_in[0];
    const float* edge_attr = (const float*)d_in[1];
    const float* We        = (const float*)d_in[2];
    const float* be        = (const float*)d_in[3];
    const float* W1        = (const float*)d_in[4];
    const float* b1        = (const float*)d_in[5];
    const float* W2        = (const float*)d_in[6];
    const float* b2        = (const float*)d_in[7];
    const float* gamma     = (const float*)d_in[8];
    const float* beta      = (const float*)d_in[9];
    const int* edge_index  = (const int*)d_in[10];
    const int* batch       = (const int*)d_in[11];

    float* zz = (float*)d_out;
    float* g  = zz + (size_t)N_NODES * 192;

    char* ws = (char*)d_ws;
    size_t off = 0;
    auto alloc = [&](size_t bytes) {
        void* p = ws + off;
        off = (off + bytes + 255) & ~(size_t)255;
        return p;
    };
    int* hist        = (int*)alloc((size_t)N_NODES * 4);
    int* row_start   = (int*)alloc((size_t)(N_NODES + 1) * 4);
    int* cursor      = (int*)alloc((size_t)(N_NODES + 1) * 4);
    int* partial     = (int*)alloc(64 * 4);
    int* cbase       = (int*)alloc(64 * 4);
    int2* es_sorted  = (int2*)alloc((size_t)N_EDGES * 8);          // 12.8 MB
    int* src_sorted  = (int*)alloc((size_t)N_EDGES * 4);           // 6.4 MB
    _Float16* ea16   = (_Float16*)alloc((size_t)N_EDGES * 16 * 2); // 51.2 MB
    _Float16* x16    = (_Float16*)alloc((size_t)N_NODES * 64 * 2); // 12.8 MB
    _Float16* z16    = (_Float16*)alloc((size_t)N_NODES * 64 * 2); // 12.8 MB
    float* hin       = (float*)alloc((size_t)N_NODES * 64 * 4);
    float* hout      = (float*)alloc((size_t)N_NODES * 64 * 4);
    float* ssum      = (float*)alloc((size_t)N_LAYERS * 64 * 4);
    float* ssq       = (float*)alloc((size_t)N_LAYERS * 64 * 4);

    // CSR build
    hipMemsetAsync(hist, 0, (size_t)N_NODES * 4, stream);
    k_hist<<<(N_EDGES + 255) / 256, 256, 0, stream>>>(edge_index + N_EDGES, hist);
    k_scan_partial<<<NCHUNK, 256, 0, stream>>>(hist, partial);
    k_scan_base<<<1, 64, 0, stream>>>(partial, cbase);
    k_scan_final<<<NCHUNK, 256, 0, stream>>>(hist, cbase, row_start, cursor);
    k_fill_es<<<(N_EDGES + 255) / 256, 256, 0, stream>>>(edge_index, cursor, es_sorted);
    k_gather<<<(N_EDGES * 4 + 255) / 256, 256, 0, stream>>>(
        es_sorted, edge_attr, ea16, src_sorted);
    k_cvt_x<<<(N_NODES * 16 + 255) / 256, 256, 0, stream>>>(x, x16);

    hipMemsetAsync(g, 0, (size_t)N_GRAPHS * 192 * 4, stream);
    hipMemsetAsync(ssum, 0, (size_t)N_LAYERS * 64 * 4, stream);
    hipMemsetAsync(ssq, 0, (size_t)N_LAYERS * 64 * 4, stream);

    for (int l = 0; l < N_LAYERS; ++l) {
        const float* zself = (l == 0) ? x : (zz + (size_t)(l - 1) * 64);
        int zstride = (l == 0) ? 64 : 192;
        const _Float16* zsrc16 = (l == 0) ? x16 : z16;
        k_aggregate<<<(N_NODES * 64 + 255) / 256, 256, 0, stream>>>(
            zself, zstride, zsrc16,
            We + (size_t)l * EDGE_DIM * 64, be + (size_t)l * 64,
            row_start, src_sorted, ea16, hin);
        k_mlp<<<(N_NODES + 255) / 256, 256, 0, stream>>>(
            hin, W1 + (size_t)l * 4096, b1 + (size_t)l * 64,
            W2 + (size_t)l * 4096, b2 + (size_t)l * 64, hout);
        k_stats<<<256, 256, 0, stream>>>(hout, ssum + l * 64, ssq + l * 64);
        k_norm<<<(N_NODES * 16 + 255) / 256, 256, 0, stream>>>(
            hout, ssum + l * 64, ssq + l * 64,
            gamma + (size_t)l * 64, beta + (size_t)l * 64,
            zz + (size_t)l * 64, (l < N_LAYERS - 1) ? z16 : (_Float16*)nullptr);
    }
    k_graph<<<(N_NODES + GNODES - 1) / GNODES, 192, 0, stream>>>(zz, batch, g);
}